// Round 6
// baseline (315.818 us; speedup 1.0000x reference)
//
#include <hip/hip_runtime.h>

#define TPB 256
#define NBLK 256          // blocks for edge-streaming phases
#define BSH 8             // node >> 8 -> bucket; 256 nodes per bucket

typedef __attribute__((ext_vector_type(4))) float f32x4;
typedef __attribute__((ext_vector_type(8))) short short8;

__device__ __forceinline__ unsigned short f2bf(float f) {
    unsigned u = __float_as_uint(f);
    u = (u + 0x7fffu + ((u >> 16) & 1u)) >> 16;
    return (unsigned short)u;
}
__device__ __forceinline__ float bflo(unsigned u) { return __uint_as_float(u << 16); }
__device__ __forceinline__ float bfhi(unsigned u) { return __uint_as_float(u & 0xffff0000u); }

// ============ pass 1: per-node degree (global atomics) + bucket totals + W->bf16 =
// deg[] and ctot[] are pre-zeroed by a hipMemsetAsync before this launch.

__global__ __launch_bounds__(256) void k_hist(const int* __restrict__ dst,
                                              int* __restrict__ deg,
                                              int* __restrict__ ctot,
                                              const float* __restrict__ W,
                                              unsigned short* __restrict__ wbf, int E) {
    __shared__ int sh[512];
    int t = threadIdx.x;
    sh[t] = 0; sh[t + 256] = 0;
    __syncthreads();
    int chunk = (E + NBLK - 1) / NBLK;
    int lo = blockIdx.x * chunk;
    int hi = min(E, lo + chunk);
    for (int e = lo + t; e < hi; e += 256) {
        int d = dst[e];
        atomicAdd(&deg[d], 1);                 // per-node degree (L2-resident 400 KB)
        atomicAdd(&sh[d >> BSH], 1);           // per-block bucket hist (LDS)
    }
    __syncthreads();
    if (sh[t])       atomicAdd(&ctot[t],       sh[t]);        // bucket totals
    if (sh[t + 256]) atomicAdd(&ctot[t + 256], sh[t + 256]);

    // hoisted W -> bf16 conversion (used only by gemm half of pass 3)
    if (blockIdx.x < 8) {
        int gid = blockIdx.x * 256 + t;        // 0..2047, 8 floats each (128x128)
        const float* wp = W + gid * 8;
        float4 w0 = *(const float4*)wp;
        float4 w1 = *(const float4*)(wp + 4);
        union { unsigned short u[8]; uint4 q; } pk;
        pk.u[0] = f2bf(w0.x); pk.u[1] = f2bf(w0.y); pk.u[2] = f2bf(w0.z); pk.u[3] = f2bf(w0.w);
        pk.u[4] = f2bf(w1.x); pk.u[5] = f2bf(w1.y); pk.u[6] = f2bf(w1.z); pk.u[7] = f2bf(w1.w);
        *((uint4*)wbf + gid) = pk.q;
    }
}

// local helper: exclusive scan of ctot[512] into bb[513] (LDS), 256 threads.
__device__ __forceinline__ void bucket_base_scan(const int* __restrict__ ctot,
                                                 int* tp0, int* tp1, int* bb,
                                                 int E, int t) {
    int v0 = ctot[2 * t], v1 = ctot[2 * t + 1];
    int p = v0 + v1;
    tp0[t] = p;
    __syncthreads();
    int sb = 0;
    for (int d = 1; d < 256; d <<= 1) {
        int* cur = sb ? tp1 : tp0;
        int* nxt = sb ? tp0 : tp1;
        int val = cur[t] + ((t >= d) ? cur[t - d] : 0);
        nxt[t] = val;
        sb ^= 1;
        __syncthreads();
    }
    int* fin = sb ? tp1 : tp0;
    int base = fin[t] - p;                     // exclusive pair base
    bb[2 * t] = base;
    bb[2 * t + 1] = base + v0;
    if (t == 0) bb[512] = E;
    __syncthreads();
}

// ============ pass 2: CSR offsets + scatter cursors + dinv ============
// One block per 256-node bucket: redundant bb-scan (sub-µs) + intra-bucket scan
// of deg. Writes offsets[d], gcur[d] (scatter cursor), dinv[d].

__global__ __launch_bounds__(256) void k_offs(const int* __restrict__ ctot,
                                              const int* __restrict__ deg,
                                              int* __restrict__ offsets,
                                              int* __restrict__ gcur,
                                              float* __restrict__ dinv, int N, int E) {
    __shared__ int tp0[256], tp1[256];
    __shared__ int bb[513];
    int t = threadIdx.x;
    bucket_base_scan(ctot, tp0, tp1, bb, E, t);

    int b = blockIdx.x;
    int d = (b << BSH) + t;
    int v = (d < N) ? deg[d] : 0;
    tp0[t] = v;
    __syncthreads();
    int sb = 0;
    for (int dl = 1; dl < 256; dl <<= 1) {
        int* cur = sb ? tp1 : tp0;
        int* nxt = sb ? tp0 : tp1;
        int val = cur[t] + ((t >= dl) ? cur[t - dl] : 0);
        nxt[t] = val;
        sb ^= 1;
        __syncthreads();
    }
    int* fin = sb ? tp1 : tp0;
    int lbase = fin[t] - v;                    // bucket-local exclusive base
    if (d < N) {
        int off = bb[b] + lbase;
        offsets[d] = off;
        gcur[d]    = off;
        dinv[d]    = rsqrtf((float)v + 1.0f);
    }
    if (b == 0 && t == 0) offsets[N] = E;
}

// ============ pass 3: atomic-cursor scatter (blocks 0..NBLK-1) || gemm (rest) ====
// scatter: sorted_src[atomicAdd(gcur[dst])] = src<<8 (byte offset of g-row).
//   Order within a dst's list is nondeterministic — f32 sum reorder only.
// gemm: g[i][j] = bf16( dinv[i] * sum_k x[i][k]*W[j][k] )  (dinv ready from pass 2,
//   so the aggregate reverts to its proven pure-add form).

__global__ __launch_bounds__(256) void k_scatgemm(
    const int* __restrict__ src, const int* __restrict__ dst,
    int* __restrict__ gcur, int* __restrict__ sorted_src,
    const float* __restrict__ x, const unsigned short* __restrict__ wbf,
    const float* __restrict__ dinv, unsigned short* __restrict__ g, int N, int E)
{
    __shared__ __align__(16) unsigned short wb[128][136];
    const int t = threadIdx.x;

    if (blockIdx.x < NBLK) {
        // ---------------- scatter half ----------------
        int chunk = (E + NBLK - 1) / NBLK;
        int lo = blockIdx.x * chunk;
        int hi = min(E, lo + chunk);
        for (int e = lo + t; e < hi; e += 256) {
            int d = dst[e];
            int s = src[e];
            int pos = atomicAdd(&gcur[d], 1);  // global cursor (L2-resident 400 KB)
            sorted_src[pos] = s << 8;          // byte offset of g-row (src*256)
        }
    } else {
        // ---------------- gemm half ----------------
        const uint4* wv = (const uint4*)wbf;
        for (int ch = t; ch < 2048; ch += 256) {
            int nrow = ch >> 4, k8 = (ch & 15) << 3;
            *(uint4*)&wb[nrow][k8] = wv[ch];   // 8 bf16, 16B aligned
        }
        __syncthreads();

        const int lane = t & 63;
        const int wid  = t >> 6;
        const int l15  = lane & 15;
        const int quad = lane >> 4;
        const int row  = (blockIdx.x - NBLK) * 64 + wid * 16 + l15;
        const int rowc = (row < N) ? row : (N - 1);

        f32x4 acc[8];
        #pragma unroll
        for (int u = 0; u < 8; ++u) acc[u] = (f32x4){0.f, 0.f, 0.f, 0.f};

        #pragma unroll
        for (int ks = 0; ks < 4; ++ks) {
            const int kb = ks * 32 + quad * 8;
            float4 a0 = *(const float4*)(x + (long)rowc * 128 + kb);
            float4 a1 = *(const float4*)(x + (long)rowc * 128 + kb + 4);
            union { unsigned short u[8]; short8 v; } af;
            af.u[0] = f2bf(a0.x); af.u[1] = f2bf(a0.y); af.u[2] = f2bf(a0.z); af.u[3] = f2bf(a0.w);
            af.u[4] = f2bf(a1.x); af.u[5] = f2bf(a1.y); af.u[6] = f2bf(a1.z); af.u[7] = f2bf(a1.w);
            #pragma unroll
            for (int u = 0; u < 8; ++u) {
                short8 bf = *(const short8*)&wb[u * 16 + l15][kb];
                // swapped: W frag as A, x frag as B  ->  D[j][i]
                acc[u] = __builtin_amdgcn_mfma_f32_16x16x32_bf16(bf, af.v, acc[u], 0, 0, 0);
            }
        }

        if (row < N) {
            float dv = dinv[row];
            unsigned short* gp = g + (long)row * 128 + quad * 4;
            #pragma unroll
            for (int u = 0; u < 8; ++u) {
                unsigned short u0 = f2bf(acc[u][0] * dv);
                unsigned short u1 = f2bf(acc[u][1] * dv);
                unsigned short u2 = f2bf(acc[u][2] * dv);
                unsigned short u3 = f2bf(acc[u][3] * dv);
                uint2 pk;
                pk.x = (unsigned)u0 | ((unsigned)u1 << 16);
                pk.y = (unsigned)u2 | ((unsigned)u3 << 16);
                *(uint2*)(gp + u * 16) = pk;   // 4 consecutive bf16 cols
            }
        }
    }
}

// ============ CSR aggregate: out[d] = dinv[d]*(g[d] + sum g[src]) + b ============
// Proven config: 32 lanes per dst, uint2 gathers, 8/4/1 ladder (VGPR ~24,
// ~70% occupancy — gather-latency-bound, needs the TLP). g is pre-scaled by
// dinv[src]; sorted_src holds byte offsets: no mul/shift in the gather address.

__global__ __launch_bounds__(256) void k_aggregate(const int* __restrict__ sorted_src,
                                                   const int* __restrict__ offsets,
                                                   const unsigned short* __restrict__ g,
                                                   const float* __restrict__ dinv,
                                                   const float* __restrict__ b,
                                                   float* __restrict__ out, int n) {
    int d = blockIdx.x * (TPB / 32) + (threadIdx.x >> 5);
    if (d >= n) return;
    int c = (threadIdx.x & 31) << 2;
    const char* gb = (const char*)g + (c << 1);   // lane base inside a g-row

    int s0 = offsets[d];
    int s1 = offsets[d + 1];

    float4 acc = make_float4(0.f, 0.f, 0.f, 0.f);
    auto addrow = [&](int off) {                  // off = byte offset of g-row
        uint2 p = *(const uint2*)(gb + off);
        acc.x += bflo(p.x); acc.y += bfhi(p.x);
        acc.z += bflo(p.y); acc.w += bfhi(p.y);
    };

    addrow(d << 8);  // self-loop (d*256 bytes)
    int e = s0;
    for (; e + 8 <= s1; e += 8) {
        int a[8];
        #pragma unroll
        for (int j = 0; j < 8; ++j) a[j] = sorted_src[e + j];
        #pragma unroll
        for (int j = 0; j < 8; ++j) addrow(a[j]);
    }
    for (; e + 4 <= s1; e += 4) {
        int a[4];
        #pragma unroll
        for (int j = 0; j < 4; ++j) a[j] = sorted_src[e + j];
        #pragma unroll
        for (int j = 0; j < 4; ++j) addrow(a[j]);
    }
    for (; e < s1; ++e) addrow(sorted_src[e]);

    float s = dinv[d];
    float4 bb = *(const float4*)(b + c);
    float4 r = make_float4(acc.x * s + bb.x, acc.y * s + bb.y,
                           acc.z * s + bb.z, acc.w * s + bb.w);
    *(float4*)(out + (long)d * 128 + c) = r;
}

// ============ launch ============

extern "C" void kernel_launch(void* const* d_in, const int* in_sizes, int n_in,
                              void* d_out, int out_size, void* d_ws, size_t ws_size,
                              hipStream_t stream) {
    const float* x  = (const float*)d_in[0];
    const int*   ei = (const int*)d_in[1];
    // d_in[2] = edge_attr (unused; GCN edge weight = 1)
    const float* W  = (const float*)d_in[3];
    const float* b  = (const float*)d_in[4];
    float* out = (float*)d_out;

    const int N = in_sizes[0] / 128;
    const int E = in_sizes[1] / 2;
    const int* src = ei;
    const int* dst = ei + E;
    const int NB = (N + 255) >> BSH;   // 391 buckets (<= 512)

    // ---- workspace carve (~34 MB) ----
    char* p = (char*)d_ws;
    auto carve = [&](size_t bytes) { char* q = p; p += (bytes + 255) & ~(size_t)255; return q; };
    int*            deg        = (int*)           carve((size_t)N * 4);
    int*            ctot       = (int*)           carve(512 * 4);
    int*            offsets    = (int*)           carve((size_t)(N + 1) * 4);
    int*            gcur       = (int*)           carve((size_t)N * 4);
    float*          dinv       = (float*)         carve((size_t)N * 4);
    int*            sorted_src = (int*)           carve((size_t)E * 4);
    unsigned short* wbf        = (unsigned short*)carve((size_t)128 * 128 * 2);
    unsigned short* g          = (unsigned short*)carve((size_t)N * 128 * 2);

    const int gemmBlocks = (N + 63) / 64;

    // zero deg + ctot (contiguous carves) in one memset
    size_t zbytes = (size_t)((char*)(ctot + 512) - (char*)deg);
    hipMemsetAsync(deg, 0, zbytes, stream);

    k_hist    <<<NBLK, TPB, 0, stream>>>(dst, deg, ctot, W, wbf, E);
    k_offs    <<<NB, TPB, 0, stream>>>(ctot, deg, offsets, gcur, dinv, N, E);
    k_scatgemm<<<NBLK + gemmBlocks, TPB, 0, stream>>>(src, dst, gcur, sorted_src,
                                                      x, wbf, dinv, g, N, E);

    k_aggregate<<<(N + (TPB / 32) - 1) / (TPB / 32), TPB, 0, stream>>>(
        sorted_src, offsets, g, dinv, b, out, N);
}

// Round 7
// 231.735 us; speedup vs baseline: 1.3628x; 1.3628x over previous
//
#include <hip/hip_runtime.h>

#define TPB 256
#define NBLK 256          // scatter blocks in the fused kernel
#define BSH 8             // node >> 8 -> bucket; 256 nodes per bucket
#define BCAP 6144         // fixed packed-region size per bucket (mean 4092, +32sigma)

typedef __attribute__((ext_vector_type(4))) float f32x4;
typedef __attribute__((ext_vector_type(8))) short short8;

__device__ __forceinline__ unsigned short f2bf(float f) {
    unsigned u = __float_as_uint(f);
    u = (u + 0x7fffu + ((u >> 16) & 1u)) >> 16;
    return (unsigned short)u;
}
__device__ __forceinline__ float bflo(unsigned u) { return __uint_as_float(u << 16); }
__device__ __forceinline__ float bfhi(unsigned u) { return __uint_as_float(u & 0xffff0000u); }

// ============ pass 1 (fused): bucket scatter (blocks 0..NBLK-1) || gemm (rest) ====
// Scatter: LDS chunk-hist -> 512 global base-grab atomics (2 per THREAD, not per
// edge — R6's per-edge returning atomic was the 92 us disaster) -> LDS-cursor
// scatter into FIXED per-bucket regions packed[b*BCAP ..]. Fixed regions remove
// the need for any cross-block prefix before scattering.
// Gemm: g[i][j] = bf16( sum_k x[i][k]*W[j][k] ), UNSCALED (dinv applied in
// aggregate) so it needs nothing from preprocessing. W converted per-block
// from f32 (R0-proven staging).

__global__ __launch_bounds__(256) void k_scatgemm(
    const int* __restrict__ src, const int* __restrict__ dst,
    int* __restrict__ bcur, unsigned* __restrict__ packed,
    const float* __restrict__ x, const float* __restrict__ W,
    unsigned short* __restrict__ g, int N, int E)
{
    __shared__ __align__(16) char smem[34816];
    const int t = threadIdx.x;

    if (blockIdx.x < NBLK) {
        // ---------------- scatter half ----------------
        int* sh = (int*)smem;                      // 512 ints: hist, then cursors
        sh[t] = 0; sh[t + 256] = 0;
        __syncthreads();
        int chunk = (E + NBLK - 1) / NBLK;
        int lo = blockIdx.x * chunk;
        int hi = min(E, lo + chunk);
        for (int e = lo + t; e < hi; e += 256)
            atomicAdd(&sh[dst[e] >> BSH], 1);      // LDS atomic only
        __syncthreads();
        int c0 = sh[t], c1 = sh[t + 256];
        int b0 = c0 ? atomicAdd(&bcur[t],       c0) : 0;   // global base grab
        int b1 = c1 ? atomicAdd(&bcur[t + 256], c1) : 0;   // (131K total, ~1us)
        __syncthreads();
        sh[t]       = t * BCAP + b0;               // absolute cursor in packed
        sh[t + 256] = (t + 256) * BCAP + b1;
        __syncthreads();
        for (int e = lo + t; e < hi; e += 256) {
            int d = dst[e];
            int bkt = d >> BSH;
            int pos = atomicAdd(&sh[bkt], 1);      // LDS atomic
            if (pos < bkt * BCAP + BCAP)           // overflow guard (never on this input)
                packed[pos] = ((unsigned)src[e] << 8) | (unsigned)(d & 255);
        }
    } else {
        // ---------------- gemm half ----------------
        typedef unsigned short wb_t[136];
        wb_t* wb = (wb_t*)smem;                    // [128][136] bf16 = 34816 B

        for (int ch = t; ch < 2048; ch += 256) {
            int nrow = ch >> 4, k8 = (ch & 15) << 3;
            const float* wp = W + nrow * 128 + k8;
            float4 w0 = *(const float4*)wp;
            float4 w1 = *(const float4*)(wp + 4);
            union { unsigned short u[8]; uint4 q; } pk;
            pk.u[0] = f2bf(w0.x); pk.u[1] = f2bf(w0.y); pk.u[2] = f2bf(w0.z); pk.u[3] = f2bf(w0.w);
            pk.u[4] = f2bf(w1.x); pk.u[5] = f2bf(w1.y); pk.u[6] = f2bf(w1.z); pk.u[7] = f2bf(w1.w);
            *(uint4*)&wb[nrow][k8] = pk.q;
        }
        __syncthreads();

        const int lane = t & 63;
        const int wid  = t >> 6;
        const int l15  = lane & 15;
        const int quad = lane >> 4;
        const int row  = (blockIdx.x - NBLK) * 64 + wid * 16 + l15;
        const int rowc = (row < N) ? row : (N - 1);

        f32x4 acc[8];
        #pragma unroll
        for (int u = 0; u < 8; ++u) acc[u] = (f32x4){0.f, 0.f, 0.f, 0.f};

        #pragma unroll
        for (int ks = 0; ks < 4; ++ks) {
            const int kb = ks * 32 + quad * 8;
            float4 a0 = *(const float4*)(x + (long)rowc * 128 + kb);
            float4 a1 = *(const float4*)(x + (long)rowc * 128 + kb + 4);
            union { unsigned short u[8]; short8 v; } af;
            af.u[0] = f2bf(a0.x); af.u[1] = f2bf(a0.y); af.u[2] = f2bf(a0.z); af.u[3] = f2bf(a0.w);
            af.u[4] = f2bf(a1.x); af.u[5] = f2bf(a1.y); af.u[6] = f2bf(a1.z); af.u[7] = f2bf(a1.w);
            #pragma unroll
            for (int u = 0; u < 8; ++u) {
                short8 bf = *(const short8*)&wb[u * 16 + l15][kb];
                // swapped: W frag as A, x frag as B  ->  D[j][i]
                acc[u] = __builtin_amdgcn_mfma_f32_16x16x32_bf16(bf, af.v, acc[u], 0, 0, 0);
            }
        }

        if (row < N) {
            unsigned short* gp = g + (long)row * 128 + quad * 4;
            #pragma unroll
            for (int u = 0; u < 8; ++u) {
                unsigned short u0 = f2bf(acc[u][0]);
                unsigned short u1 = f2bf(acc[u][1]);
                unsigned short u2 = f2bf(acc[u][2]);
                unsigned short u3 = f2bf(acc[u][3]);
                uint2 pk;
                pk.x = (unsigned)u0 | ((unsigned)u1 << 16);
                pk.y = (unsigned)u2 | ((unsigned)u3 << 16);
                *(uint2*)(gp + u * 16) = pk;       // 4 consecutive bf16 cols
            }
        }
    }
}

// ============ pass 2: per-bucket exact CSR + offsets + dinv ============
// Reads each bucket's fixed region, sorts by dst-local into compact sorted_src.
// Global sorted bases come from a redundant sub-us LDS scan of the bucket counts.

__global__ __launch_bounds__(256) void k_bcsr(const unsigned* __restrict__ packed,
                                              const int* __restrict__ bcur,
                                              int* __restrict__ offsets,
                                              int* __restrict__ sorted_src,
                                              float* __restrict__ dinv, int N, int E, int NB) {
    __shared__ int tp0[256], tp1[256];
    __shared__ int bb[513];
    __shared__ int hist[256];
    __shared__ int scur[256];
    __shared__ unsigned stage[BCAP];
    int t = threadIdx.x;

    // exclusive scan of bucket counts -> global sorted bases bb[513]
    {
        int v0 = bcur[2 * t], v1 = bcur[2 * t + 1];
        int p = v0 + v1;
        tp0[t] = p;
        __syncthreads();
        int sb = 0;
        for (int d = 1; d < 256; d <<= 1) {
            int* cur = sb ? tp1 : tp0;
            int* nxt = sb ? tp0 : tp1;
            int val = cur[t] + ((t >= d) ? cur[t - d] : 0);
            nxt[t] = val;
            sb ^= 1;
            __syncthreads();
        }
        int* fin = sb ? tp1 : tp0;
        int base = fin[t] - p;
        bb[2 * t] = base;
        bb[2 * t + 1] = base + v0;
        if (t == 0) bb[512] = E;
        __syncthreads();
    }

    for (int b = blockIdx.x; b < NB; b += NBLK) {
        int cnt = min(bcur[b], BCAP);
        int s0g = b * BCAP;                        // packed region start
        int o0  = bb[b];                           // global sorted base
        hist[t] = 0;
        __syncthreads();
        for (int e = t; e < cnt; e += 256)
            atomicAdd(&hist[packed[s0g + e] & 255u], 1);   // LDS atomic
        __syncthreads();
        int v = hist[t];
        tp0[t] = v;
        __syncthreads();
        int sb = 0;
        for (int d = 1; d < 256; d <<= 1) {
            int* cur = sb ? tp1 : tp0;
            int* nxt = sb ? tp0 : tp1;
            int val = cur[t] + ((t >= d) ? cur[t - d] : 0);
            nxt[t] = val;
            sb ^= 1;
            __syncthreads();
        }
        int* fin = sb ? tp1 : tp0;
        int lbase = fin[t] - v;                    // bucket-local exclusive base
        scur[t] = lbase;
        int d = (b << BSH) + t;
        if (d < N) { offsets[d] = o0 + lbase; dinv[d] = rsqrtf((float)v + 1.0f); }
        if (b == 0 && t == 0) offsets[N] = E;
        __syncthreads();
        for (int e = t; e < cnt; e += 256) {
            unsigned pk = packed[s0g + e];
            int pos = atomicAdd(&scur[pk & 255u], 1);      // LDS atomic
            stage[pos] = pk >> 8;                          // plain src index
        }
        __syncthreads();
        for (int i = t; i < cnt; i += 256)
            sorted_src[o0 + i] = (int)stage[i];            // coalesced stream-out
        __syncthreads();                           // before hist reuse next bucket
    }
}

// ============ CSR aggregate: out[d] = dinv[d]*(Σ dinv[s]*g[s] + dinv[d]*g[d]) + b =
// R5-proven form: 32 lanes per dst, uint2 gathers, 8/4/1 ladder; g is unscaled so
// each row is fma'd with dinv[s] (L2-resident 400 KB table).

__global__ __launch_bounds__(256) void k_aggregate(const int* __restrict__ sorted_src,
                                                   const int* __restrict__ offsets,
                                                   const unsigned short* __restrict__ g,
                                                   const float* __restrict__ dinv,
                                                   const float* __restrict__ b,
                                                   float* __restrict__ out, int n) {
    int d = blockIdx.x * (TPB / 32) + (threadIdx.x >> 5);
    if (d >= n) return;
    int c = (threadIdx.x & 31) << 2;
    const char* gb = (const char*)g + (c << 1);   // lane base inside a g-row

    int s0 = offsets[d];
    int s1 = offsets[d + 1];

    float4 acc = make_float4(0.f, 0.f, 0.f, 0.f);
    auto addrow = [&](int r) {                    // r = src row index
        float dv = dinv[r];
        uint2 p = *(const uint2*)(gb + (r << 8));
        acc.x = fmaf(bflo(p.x), dv, acc.x);
        acc.y = fmaf(bfhi(p.x), dv, acc.y);
        acc.z = fmaf(bflo(p.y), dv, acc.z);
        acc.w = fmaf(bfhi(p.y), dv, acc.w);
    };

    addrow(d);  // self-loop: contributes dinv[d]*g[d]
    int e = s0;
    for (; e + 8 <= s1; e += 8) {
        int a[8];
        #pragma unroll
        for (int j = 0; j < 8; ++j) a[j] = sorted_src[e + j];
        #pragma unroll
        for (int j = 0; j < 8; ++j) addrow(a[j]);
    }
    for (; e + 4 <= s1; e += 4) {
        int a[4];
        #pragma unroll
        for (int j = 0; j < 4; ++j) a[j] = sorted_src[e + j];
        #pragma unroll
        for (int j = 0; j < 4; ++j) addrow(a[j]);
    }
    for (; e < s1; ++e) addrow(sorted_src[e]);

    float s = dinv[d];
    float4 bb = *(const float4*)(b + c);
    float4 r = make_float4(acc.x * s + bb.x, acc.y * s + bb.y,
                           acc.z * s + bb.z, acc.w * s + bb.w);
    *(float4*)(out + (long)d * 128 + c) = r;
}

// ============ launch ============

extern "C" void kernel_launch(void* const* d_in, const int* in_sizes, int n_in,
                              void* d_out, int out_size, void* d_ws, size_t ws_size,
                              hipStream_t stream) {
    const float* x  = (const float*)d_in[0];
    const int*   ei = (const int*)d_in[1];
    // d_in[2] = edge_attr (unused; GCN edge weight = 1)
    const float* W  = (const float*)d_in[3];
    const float* b  = (const float*)d_in[4];
    float* out = (float*)d_out;

    const int N = in_sizes[0] / 128;
    const int E = in_sizes[1] / 2;
    const int* src = ei;
    const int* dst = ei + E;
    const int NB = (N + 255) >> BSH;   // 391 buckets (<= 512)

    // ---- workspace carve (~46 MB) ----
    char* p = (char*)d_ws;
    auto carve = [&](size_t bytes) { char* q = p; p += (bytes + 255) & ~(size_t)255; return q; };
    int*            bcur       = (int*)           carve(512 * 4);
    int*            offsets    = (int*)           carve((size_t)(N + 1) * 4);
    float*          dinv       = (float*)         carve((size_t)N * 4);
    int*            sorted_src = (int*)           carve((size_t)E * 4);
    unsigned*       packed     = (unsigned*)      carve((size_t)512 * BCAP * 4);
    unsigned short* g          = (unsigned short*)carve((size_t)N * 128 * 2);

    const int gemmBlocks = (N + 63) / 64;

    hipMemsetAsync(bcur, 0, 512 * 4, stream);      // 2 KB — only state to clear

    k_scatgemm<<<NBLK + gemmBlocks, TPB, 0, stream>>>(src, dst, bcur, packed,
                                                      x, W, g, N, E);
    k_bcsr    <<<NBLK, TPB, 0, stream>>>(packed, bcur, offsets, sorted_src,
                                         dinv, N, E, NB);
    k_aggregate<<<(N + (TPB / 32) - 1) / (TPB / 32), TPB, 0, stream>>>(
        sorted_src, offsets, g, dinv, b, out, N);
}